// Round 13
// baseline (88.999 us; speedup 1.0000x reference)
//
#include <hip/hip_runtime.h>

#define Bv 4
#define Vv 50000
#define Cv 160
#define TILES 782      // ceil(Vv/64)
#define WSTR 168       // bf16 row stride in LDS: 336 B = 21*16 (b128-aligned)

typedef unsigned short u16;
typedef unsigned int   u32;
typedef __attribute__((ext_vector_type(8))) short bf16x8;  // 8 bf16 = 4 VGPRs
typedef __attribute__((ext_vector_type(4))) float f32x4;

__device__ __forceinline__ u16 f2bf(float f) {
    u32 u = __float_as_uint(f);
    return (u16)((u + 0x7FFFu + ((u >> 16) & 1u)) >> 16);  // RNE
}

// Fused kernel: per 64-vertex tile (782 blocks x 256 thr = 4 waves).
//   P(64x48) = Wtile(64x160 bf16) x AT(160x48 bf16)   [15 mfma 16x16x32]
//   out[b, v0+vl, :] = M.x + T   (fp32 epilogue)
// AT (the per-(b,c) affine table, n = b*12+j: j 0..8 = R row-major,
// 9..11 = T = center+Vn-R*center) is computed IN-BLOCK (640 rotations,
// ~200 VALU/thread) in the latency shadow of the W staging loads —
// removing R12's separate precompute launch + dependency bubble.
// Two barriers total (P has its own LDS region).
__global__ __launch_bounds__(256) void deform_fused(const float* __restrict__ X,
                                                    const float* __restrict__ Vn,
                                                    const float* __restrict__ r6,
                                                    const int* __restrict__ idx,
                                                    const float* __restrict__ W,
                                                    float* __restrict__ out) {
    __shared__ u16   Wl[64 * WSTR];    // 21504 B
    __shared__ u16   ATl[48 * WSTR];   // 16128 B
    __shared__ float P[64 * 49];       // 12544 B   (total 50176 B -> 3 blk/CU)

    const int tid = threadIdx.x;
    const int v0  = blockIdx.x * 64;

    // --- Phase 1a: issue W staging loads (10 float4/thread) ---------------
    float4 wq[10];
#pragma unroll
    for (int t = 0; t < 10; ++t) {
        int i  = tid + t * 256;            // i in [0, 2560)
        int r  = i / 40, c4 = i % 40;
        int row = v0 + r;
        if (row >= Vv) row = Vv - 1;       // tail tile: dup rows, epilogue guards
        wq[t] = ((const float4*)(W + (size_t)row * Cv))[c4];
    }

    // --- Phase 1b: compute AT in-block (overlaps the W loads) -------------
    for (int i = tid; i < Bv * Cv; i += 256) {
        int b = i / Cv, c = i % Cv;

        const float* d6 = r6 + (size_t)(b * Cv + c) * 6;
        float a1x = d6[0], a1y = d6[1], a1z = d6[2];
        float a2x = d6[3], a2y = d6[4], a2z = d6[5];

        float n1 = fmaxf(sqrtf(a1x*a1x + a1y*a1y + a1z*a1z), 1e-8f);
        float b1x = a1x / n1, b1y = a1y / n1, b1z = a1z / n1;

        float d = b1x*a2x + b1y*a2y + b1z*a2z;
        float px = a2x - d*b1x, py = a2y - d*b1y, pz = a2z - d*b1z;
        float n2 = fmaxf(sqrtf(px*px + py*py + pz*pz), 1e-8f);
        float b2x = px / n2, b2y = py / n2, b2z = pz / n2;

        float b3x = b1y*b2z - b1z*b2y;
        float b3y = b1z*b2x - b1x*b2z;
        float b3z = b1x*b2y - b1y*b2x;

        int iv = idx[c];
        const float* xc = X + ((size_t)b * Vv + iv) * 3;
        float cx = xc[0], cy = xc[1], cz = xc[2];
        const float* vn = Vn + (size_t)(b * Cv + c) * 3;
        float vx = vn[0], vy = vn[1], vz = vn[2];

        float vals[12];
        vals[0] = b1x; vals[1]  = b1y; vals[2]  = b1z;
        vals[3] = b2x; vals[4]  = b2y; vals[5]  = b2z;
        vals[6] = b3x; vals[7]  = b3y; vals[8]  = b3z;
        vals[9]  = cx + vx - (b1x*cx + b1y*cy + b1z*cz);
        vals[10] = cy + vy - (b2x*cx + b2y*cy + b2z*cz);
        vals[11] = cz + vz - (b3x*cx + b3y*cy + b3z*cz);

#pragma unroll
        for (int j = 0; j < 12; ++j)
            ATl[(b * 12 + j) * WSTR + c] = f2bf(vals[j]);
    }

    // --- Phase 1c: convert + store W tile to LDS --------------------------
#pragma unroll
    for (int t = 0; t < 10; ++t) {
        int i  = tid + t * 256;
        int r  = i / 40, c4 = i % 40;
        ushort4 h;
        h.x = f2bf(wq[t].x); h.y = f2bf(wq[t].y);
        h.z = f2bf(wq[t].z); h.w = f2bf(wq[t].w);
        *(ushort4*)&Wl[r * WSTR + c4 * 4] = h;
    }
    __syncthreads();

    // --- Phase 2: MFMA ----------------------------------------------------
    const int lane = tid & 63;
    const int wv   = tid >> 6;     // M-tile 0..3 (rows 16wv..16wv+15)
    const int m    = lane & 15;
    const int quad = lane >> 4;

    bf16x8 afr[5];
#pragma unroll
    for (int kt = 0; kt < 5; ++kt)
        afr[kt] = *(const bf16x8*)&Wl[(wv * 16 + m) * WSTR + kt * 32 + quad * 8];

    bf16x8 bfr[3][5];
#pragma unroll
    for (int nt = 0; nt < 3; ++nt)
#pragma unroll
        for (int kt = 0; kt < 5; ++kt)
            bfr[nt][kt] = *(const bf16x8*)&ATl[(nt * 16 + m) * WSTR + kt * 32 + quad * 8];

    f32x4 acc[3] = {{0,0,0,0},{0,0,0,0},{0,0,0,0}};
#pragma unroll
    for (int kt = 0; kt < 5; ++kt)
#pragma unroll
        for (int nt = 0; nt < 3; ++nt)
            acc[nt] = __builtin_amdgcn_mfma_f32_16x16x32_bf16(afr[kt], bfr[nt][kt], acc[nt], 0, 0, 0);

    // C/D layout: col = lane&15, row = quad*4 + reg.
#pragma unroll
    for (int nt = 0; nt < 3; ++nt)
#pragma unroll
        for (int r = 0; r < 4; ++r)
            P[(wv * 16 + quad * 4 + r) * 49 + nt * 16 + m] = acc[nt][r];
    __syncthreads();

    // --- Phase 3: epilogue ------------------------------------------------
    const int b  = tid >> 6;
    const int vl = tid & 63;
    const int v  = v0 + vl;
    if (v < Vv) {
        const float* p  = &P[vl * 49 + b * 12];
        const float* xp = X + ((size_t)b * Vv + v) * 3;
        float x0 = xp[0], x1 = xp[1], x2 = xp[2];
        float* op = out + ((size_t)b * Vv + v) * 3;
        op[0] = p[0]*x0 + p[1]*x1 + p[2]*x2 + p[9];
        op[1] = p[3]*x0 + p[4]*x1 + p[5]*x2 + p[10];
        op[2] = p[6]*x0 + p[7]*x1 + p[8]*x2 + p[11];
    }
}

extern "C" void kernel_launch(void* const* d_in, const int* in_sizes, int n_in,
                              void* d_out, int out_size, void* d_ws, size_t ws_size,
                              hipStream_t stream) {
    const float* X   = (const float*)d_in[0];  // (B,V,3) fp32
    const float* Vn  = (const float*)d_in[1];  // (B,C,3) fp32
    const float* r6  = (const float*)d_in[2];  // (B,C,6) fp32
    const float* W   = (const float*)d_in[3];  // (V,C)   fp32
    const int*   idx = (const int*)d_in[4];    // (C,)    int32
    float* out = (float*)d_out;                // (B,V,3) fp32

    deform_fused<<<TILES, 256, 0, stream>>>(X, Vn, r6, idx, W, out);
}

// Round 14
// 88.200 us; speedup vs baseline: 1.0091x; 1.0091x over previous
//
#include <hip/hip_runtime.h>

#define Bv 4
#define Vv 50000
#define Cv 160
#define TILES 782      // ceil(Vv/64)
#define WSTR 168       // bf16 row stride in LDS: 336 B = 21*16 (b128-aligned)

typedef unsigned short u16;
typedef unsigned int   u32;
typedef __attribute__((ext_vector_type(8))) short bf16x8;  // 8 bf16 = 4 VGPRs
typedef __attribute__((ext_vector_type(4))) float f32x4;

__device__ __forceinline__ u16 f2bf(float f) {
    u32 u = __float_as_uint(f);
    return (u16)((u + 0x7FFFu + ((u >> 16) & 1u)) >> 16);  // RNE
}

// Fused kernel (R13 structure, slimmed LDS):
//   P(64x48) = Wtile(64x160 bf16) x AT(160x48 bf16)  [15 mfma 16x16x32/wave]
//   out[b, v0+vl, :] = M.x + T  (fp32 epilogue)
// LDS: P aliases Wl (all A-frag reads complete before P writes; one extra
// barrier) -> 37.6 KB vs R13's 50.2 KB -> 4 blocks/CU instead of 3. The
// extra resident block is the latency-hiding pool for the W staging loads
// and the AT input gathers (the R13 bottleneck).
__global__ __launch_bounds__(256) void deform_fused(const float* __restrict__ X,
                                                    const float* __restrict__ Vn,
                                                    const float* __restrict__ r6,
                                                    const int* __restrict__ idx,
                                                    const float* __restrict__ W,
                                                    float* __restrict__ out) {
    __shared__ char smem[64 * WSTR * 2 + 48 * WSTR * 2];  // 21504 + 16128 = 37632 B
    u16*   Wl  = (u16*)smem;
    u16*   ATl = (u16*)(smem + 64 * WSTR * 2);
    float* P   = (float*)smem;            // aliases Wl (64*49*4 = 12544 B fits)

    const int tid = threadIdx.x;
    const int v0  = blockIdx.x * 64;

    // --- Phase 1a: issue W staging loads (10 float4/thread) ---------------
    float4 wq[10];
#pragma unroll
    for (int t = 0; t < 10; ++t) {
        int i  = tid + t * 256;            // i in [0, 2560)
        int r  = i / 40, c4 = i % 40;
        int row = v0 + r;
        if (row >= Vv) row = Vv - 1;       // tail tile: dup rows, epilogue guards
        wq[t] = ((const float4*)(W + (size_t)row * Cv))[c4];
    }

    // --- Phase 1a': issue epilogue X load early (consumed in phase 3) -----
    const int eb  = tid >> 6;              // epilogue batch
    const int evl = tid & 63;              // epilogue local vertex
    const int ev  = v0 + evl;
    const int evc = (ev < Vv) ? ev : (Vv - 1);
    const float* exp_ = X + ((size_t)eb * Vv + evc) * 3;
    float ex0 = exp_[0], ex1 = exp_[1], ex2 = exp_[2];

    // --- Phase 1b: compute AT in-block (overlaps the loads above) ---------
    for (int i = tid; i < Bv * Cv; i += 256) {
        int b = i / Cv, c = i % Cv;

        const float* d6 = r6 + (size_t)(b * Cv + c) * 6;
        float a1x = d6[0], a1y = d6[1], a1z = d6[2];
        float a2x = d6[3], a2y = d6[4], a2z = d6[5];

        float n1 = fmaxf(sqrtf(a1x*a1x + a1y*a1y + a1z*a1z), 1e-8f);
        float b1x = a1x / n1, b1y = a1y / n1, b1z = a1z / n1;

        float d = b1x*a2x + b1y*a2y + b1z*a2z;
        float px = a2x - d*b1x, py = a2y - d*b1y, pz = a2z - d*b1z;
        float n2 = fmaxf(sqrtf(px*px + py*py + pz*pz), 1e-8f);
        float b2x = px / n2, b2y = py / n2, b2z = pz / n2;

        float b3x = b1y*b2z - b1z*b2y;
        float b3y = b1z*b2x - b1x*b2z;
        float b3z = b1x*b2y - b1y*b2x;

        int iv = idx[c];
        const float* xc = X + ((size_t)b * Vv + iv) * 3;
        float cx = xc[0], cy = xc[1], cz = xc[2];
        const float* vn = Vn + (size_t)(b * Cv + c) * 3;
        float vx = vn[0], vy = vn[1], vz = vn[2];

        float vals[12];
        vals[0] = b1x; vals[1]  = b1y; vals[2]  = b1z;
        vals[3] = b2x; vals[4]  = b2y; vals[5]  = b2z;
        vals[6] = b3x; vals[7]  = b3y; vals[8]  = b3z;
        vals[9]  = cx + vx - (b1x*cx + b1y*cy + b1z*cz);
        vals[10] = cy + vy - (b2x*cx + b2y*cy + b2z*cz);
        vals[11] = cz + vz - (b3x*cx + b3y*cy + b3z*cz);

#pragma unroll
        for (int j = 0; j < 12; ++j)
            ATl[(b * 12 + j) * WSTR + c] = f2bf(vals[j]);
    }

    // --- Phase 1c: convert + store W tile to LDS --------------------------
#pragma unroll
    for (int t = 0; t < 10; ++t) {
        int i  = tid + t * 256;
        int r  = i / 40, c4 = i % 40;
        ushort4 h;
        h.x = f2bf(wq[t].x); h.y = f2bf(wq[t].y);
        h.z = f2bf(wq[t].z); h.w = f2bf(wq[t].w);
        *(ushort4*)&Wl[r * WSTR + c4 * 4] = h;
    }
    __syncthreads();

    // --- Phase 2: fragment loads + MFMA -----------------------------------
    const int lane = tid & 63;
    const int wv   = tid >> 6;     // M-tile 0..3 (rows 16wv..16wv+15)
    const int m    = lane & 15;
    const int quad = lane >> 4;

    bf16x8 afr[5];
#pragma unroll
    for (int kt = 0; kt < 5; ++kt)
        afr[kt] = *(const bf16x8*)&Wl[(wv * 16 + m) * WSTR + kt * 32 + quad * 8];

    bf16x8 bfr[3][5];
#pragma unroll
    for (int nt = 0; nt < 3; ++nt)
#pragma unroll
        for (int kt = 0; kt < 5; ++kt)
            bfr[nt][kt] = *(const bf16x8*)&ATl[(nt * 16 + m) * WSTR + kt * 32 + quad * 8];

    f32x4 acc[3] = {{0,0,0,0},{0,0,0,0},{0,0,0,0}};
#pragma unroll
    for (int kt = 0; kt < 5; ++kt)
#pragma unroll
        for (int nt = 0; nt < 3; ++nt)
            acc[nt] = __builtin_amdgcn_mfma_f32_16x16x32_bf16(afr[kt], bfr[nt][kt], acc[nt], 0, 0, 0);

    __syncthreads();   // all Wl frag reads done -> safe to overwrite as P

    // C/D layout: col = lane&15, row = quad*4 + reg. P[v_local][n], stride 49.
#pragma unroll
    for (int nt = 0; nt < 3; ++nt)
#pragma unroll
        for (int r = 0; r < 4; ++r)
            P[(wv * 16 + quad * 4 + r) * 49 + nt * 16 + m] = acc[nt][r];
    __syncthreads();

    // --- Phase 3: epilogue (X already in registers) -----------------------
    if (ev < Vv) {
        const float* p = &P[evl * 49 + eb * 12];
        float* op = out + ((size_t)eb * Vv + ev) * 3;
        op[0] = p[0]*ex0 + p[1]*ex1 + p[2]*ex2 + p[9];
        op[1] = p[3]*ex0 + p[4]*ex1 + p[5]*ex2 + p[10];
        op[2] = p[6]*ex0 + p[7]*ex1 + p[8]*ex2 + p[11];
    }
}

extern "C" void kernel_launch(void* const* d_in, const int* in_sizes, int n_in,
                              void* d_out, int out_size, void* d_ws, size_t ws_size,
                              hipStream_t stream) {
    const float* X   = (const float*)d_in[0];  // (B,V,3) fp32
    const float* Vn  = (const float*)d_in[1];  // (B,C,3) fp32
    const float* r6  = (const float*)d_in[2];  // (B,C,6) fp32
    const float* W   = (const float*)d_in[3];  // (V,C)   fp32
    const int*   idx = (const int*)d_in[4];    // (C,)    int32
    float* out = (float*)d_out;                // (B,V,3) fp32

    deform_fused<<<TILES, 256, 0, stream>>>(X, Vn, r6, idx, W, out);
}